// Round 9
// baseline (127.069 us; speedup 1.0000x reference)
//
#include <hip/hip_runtime.h>

#define DD 8
#define HW 16384
#define KK 256
#define NPIX 524288
#define NG 4                           // pipeline depth: 4 px/thread
#define NBLK 512                       // 1024 px per block

#define Y_OFF    4194304UL             // B*D*H*W
#define REP_OFF  4718592UL             // + B*H*W
#define LOSS_OFF 138936320UL           // + B*H*W*K

typedef float f4 __attribute__((ext_vector_type(4)));

// barrier that orders LDS only — does NOT drain the nt-store queue (vmcnt),
// so streamed stores from stage g keep draining during stage g+1's compute
__device__ __forceinline__ void lds_barrier() {
    asm volatile("s_waitcnt lgkmcnt(0)\n\ts_barrier" ::: "memory");
}

// ---- fused: 4-deep pipeline — compute group g while streaming group g-1 ----
__global__ __launch_bounds__(256) void vq_fused_kernel(
    const float* __restrict__ q, const float* __restrict__ cb,
    float* __restrict__ emb, float* __restrict__ yf, float* __restrict__ rep,
    int* __restrict__ hist, float* __restrict__ partial)
{
    __shared__ float sc2[KK];
    __shared__ int   sy[NG][256];
    __shared__ int   shist[KK];
    __shared__ float swred[4];

    const int tid  = threadIdx.x;
    const int wid  = tid >> 6;
    const int lane = tid & 63;
    shist[tid] = 0;

    {   // ||c||^2 in-block (same expression/bits as prior rounds)
        const f4 c01 = *(const f4*)(cb + tid*8);
        const f4 c23 = *(const f4*)(cb + tid*8 + 4);
        sc2[tid] = ((c01.x*c01.x + c01.y*c01.y) + (c01.z*c01.z + c01.w*c01.w))
                 + ((c23.x*c23.x + c23.y*c23.y) + (c23.z*c23.z + c23.w*c23.w));
    }

    const int pixBase = blockIdx.x << 10;    // 1024 consecutive pixels, one image
    const int b   = pixBase >> 14;
    const int hw0 = pixBase & (HW - 1);
    const float* qb = q + (size_t)b * (DD*HW);
    float* eb = emb + (size_t)b * (DD*HW);

    // load all 4 pixels up front (one burst; latency hidden under stage-0)
    float xs[NG][DD];
    float xn[NG];
#pragma unroll
    for (int g = 0; g < NG; ++g) {
        const int hw = hw0 + (g << 8) + tid;
#pragma unroll
        for (int d = 0; d < DD; ++d) xs[g][d] = qb[d*HW + hw];
        xn[g] = ((xs[g][0]*xs[g][0] + xs[g][1]*xs[g][1]) + (xs[g][2]*xs[g][2] + xs[g][3]*xs[g][3]))
              + ((xs[g][4]*xs[g][4] + xs[g][5]*xs[g][5]) + (xs[g][6]*xs[g][6] + xs[g][7]*xs[g][7]));
    }

    lds_barrier();   // sc2 + shist ready

    float err = 0.f;
    const int b4 = lane << 2;

#pragma unroll
    for (int g = 0; g < NG; ++g) {
        // t = (x2 - 2xc) + c2 with strict <  ==  reference -0.5*t with strict >
        float best = 3.4e38f;
        int   yb   = 0;

        if (g == 0) {
#pragma unroll 4
            for (int k = 0; k < KK; ++k) {
                const f4 c01 = *(const f4*)(cb + (k << 3));   // lane-invariant -> s_load
                const f4 c23 = *(const f4*)(cb + (k << 3) + 4);
                const float c2k = sc2[k];
                float dot = 0.f;
                dot = fmaf(xs[0][0], c01.x, dot);
                dot = fmaf(xs[0][1], c01.y, dot);
                dot = fmaf(xs[0][2], c01.z, dot);
                dot = fmaf(xs[0][3], c01.w, dot);
                dot = fmaf(xs[0][4], c23.x, dot);
                dot = fmaf(xs[0][5], c23.y, dot);
                dot = fmaf(xs[0][6], c23.z, dot);
                dot = fmaf(xs[0][7], c23.w, dot);
                const float t = (xn[0] - 2.0f*dot) + c2k;
                if (t < best) { best = t; yb = k; }
            }
        } else {
            // stream group g-1's folded one-hot rows under this k-loop
            const int* syp = sy[g - 1];
            f4* repp = (f4*)rep + (((size_t)(pixBase + ((g - 1) << 8) + (wid << 6))) << 6) + lane;
            for (int c = 0; c < 64; ++c) {
#pragma unroll
                for (int j = 0; j < 4; ++j) {
                    const int k = (c << 2) + j;
                    const f4 c01 = *(const f4*)(cb + (k << 3));
                    const f4 c23 = *(const f4*)(cb + (k << 3) + 4);
                    const float c2k = sc2[k];
                    float dot = 0.f;
                    dot = fmaf(xs[g][0], c01.x, dot);
                    dot = fmaf(xs[g][1], c01.y, dot);
                    dot = fmaf(xs[g][2], c01.z, dot);
                    dot = fmaf(xs[g][3], c01.w, dot);
                    dot = fmaf(xs[g][4], c23.x, dot);
                    dot = fmaf(xs[g][5], c23.y, dot);
                    dot = fmaf(xs[g][6], c23.z, dot);
                    dot = fmaf(xs[g][7], c23.w, dot);
                    const float t = (xn[g] - 2.0f*dot) + c2k;
                    if (t < best) { best = t; yb = k; }
                }
                const int ya = syp[(wid << 6) + c];   // wave-uniform LDS broadcast
                f4 v;
                v.x = (ya == b4    ) ? 1.0f : 0.0f;
                v.y = (ya == b4 + 1) ? 1.0f : 0.0f;
                v.z = (ya == b4 + 2) ? 1.0f : 0.0f;
                v.w = (ya == b4 + 3) ? 1.0f : 0.0f;
                __builtin_nontemporal_store(v, repp + ((size_t)c << 6));
            }
        }

        // per-pixel outputs for group g: emb, err, y
        {
            const f4 cy01 = *(const f4*)(cb + (yb << 3));
            const f4 cy23 = *(const f4*)(cb + (yb << 3) + 4);
            const float cyv[DD] = {cy01.x, cy01.y, cy01.z, cy01.w,
                                   cy23.x, cy23.y, cy23.z, cy23.w};
            const int hw = hw0 + (g << 8) + tid;
#pragma unroll
            for (int d = 0; d < DD; ++d) {
                eb[d*HW + hw] = cyv[d];
                const float dd = cyv[d] - xs[g][d];
                err = fmaf(dd, dd, err);
            }
        }
        yf[pixBase + (g << 8) + tid] = (float)yb;
        sy[g][tid] = yb;
        atomicAdd(&shist[yb], 1);

        lds_barrier();   // sy[g] visible to all waves; nt stores keep draining
    }

    // final stream: group NG-1 (tight, store-bound)
    {
        const int* syl = sy[NG - 1];
        f4* repl = (f4*)rep + (((size_t)(pixBase + ((NG - 1) << 8) + (wid << 6))) << 6) + lane;
        for (int c = 0; c < 64; ++c) {
            const int ya = syl[(wid << 6) + c];
            f4 v;
            v.x = (ya == b4    ) ? 1.0f : 0.0f;
            v.y = (ya == b4 + 1) ? 1.0f : 0.0f;
            v.z = (ya == b4 + 2) ? 1.0f : 0.0f;
            v.w = (ya == b4 + 3) ? 1.0f : 0.0f;
            __builtin_nontemporal_store(v, repl + ((size_t)c << 6));
        }
    }

    // deterministic block reduction of err (4 pixels/thread accumulated)
#pragma unroll
    for (int off = 32; off; off >>= 1)
        err += __shfl_down(err, off, 64);
    if (lane == 0) swred[wid] = err;
    __syncthreads();
    if (tid == 0)
        partial[blockIdx.x] = (swred[0] + swred[1]) + (swred[2] + swred[3]);
    atomicAdd(&hist[tid], shist[tid]);   // shist complete after barrier above
}

// ---------------- finalize scalars ----------------
__global__ __launch_bounds__(256) void vq_final_kernel(
    const float* __restrict__ partial, const int* __restrict__ hist,
    float* __restrict__ outp)
{
    const int tid = threadIdx.x;
    __shared__ double sred[4];
    __shared__ double shy[4];

    double s = (double)partial[tid] + (double)partial[tid + 256];
#pragma unroll
    for (int off = 32; off; off >>= 1)
        s += __shfl_down(s, off, 64);
    if ((tid & 63) == 0) sred[tid >> 6] = s;

    float c  = (float)hist[tid];
    float py = c * (1.0f / 524288.0f);
    double ht = (double)(py * log2f(py + 1e-10f));
#pragma unroll
    for (int off = 32; off; off >>= 1)
        ht += __shfl_down(ht, off, 64);
    if ((tid & 63) == 0) shy[tid >> 6] = ht;
    __syncthreads();

    if (tid == 0) {
        double S  = (sred[0] + sred[1]) + (sred[2] + sred[3]);
        double Hy = (shy[0]  + shy[1])  + (shy[2]  + shy[3]);
        // loss = 0.5*(0.25*S/4096 + S/4096) = 0.625 * S / 4096
        outp[0] = (float)(0.625 * S / 4096.0);
        outp[1] = (float)(-Hy);
        outp[2] = 0.0f;
    }
}

extern "C" void kernel_launch(void* const* d_in, const int* in_sizes, int n_in,
                              void* d_out, int out_size, void* d_ws, size_t ws_size,
                              hipStream_t stream)
{
    const float* q  = (const float*)d_in[0];
    const float* cb = (const float*)d_in[1];
    float* out = (float*)d_out;

    float* emb = out;                     // [B,D,H,W]
    float* yf  = out + Y_OFF;             // [B,H,W] as float
    float* rep = out + REP_OFF;           // [B,H,W,K]
    float* sc  = out + LOSS_OFF;          // loss, Hy, Hyx

    float* w       = (float*)d_ws;
    int*   hist    = (int*)w;             // 256 ints
    float* partial = w + 256;             // 512 floats

    hipMemsetAsync(hist, 0, 1024, stream);   // zero hist
    vq_fused_kernel<<<NBLK, 256, 0, stream>>>(q, cb, emb, yf, rep, hist, partial);
    vq_final_kernel<<<1, 256, 0, stream>>>(partial, hist, sc);
}